// Round 1
// baseline (2886.261 us; speedup 1.0000x reference)
//
#include <hip/hip_runtime.h>

typedef unsigned int u32;
typedef unsigned char u8;

#define NBINS 32768
#define BBITS 15

__device__ inline u32 encf(float f) {
    u32 u = __float_as_uint(f);
    return (u & 0x80000000u) ? ~u : (u | 0x80000000u);
}
__device__ inline float decf(u32 e) {
    u32 b = (e & 0x80000000u) ? (e ^ 0x80000000u) : ~e;
    return __uint_as_float(b);
}

// K1: global min/max over all means (encoded-uint atomics; exact, order-independent)
__global__ void k_minmax(const float* __restrict__ means, int total, u32* __restrict__ mm) {
    float lo = 3.4e38f, hi = -3.4e38f;
    for (int i = blockIdx.x * blockDim.x + threadIdx.x; i < total; i += gridDim.x * blockDim.x) {
        float v = means[i];
        lo = fminf(lo, v);
        hi = fmaxf(hi, v);
    }
    __shared__ float slo[256], shi[256];
    slo[threadIdx.x] = lo; shi[threadIdx.x] = hi;
    __syncthreads();
    for (int s = 128; s > 0; s >>= 1) {
        if (threadIdx.x < s) {
            slo[threadIdx.x] = fminf(slo[threadIdx.x], slo[threadIdx.x + s]);
            shi[threadIdx.x] = fmaxf(shi[threadIdx.x], shi[threadIdx.x + s]);
        }
        __syncthreads();
    }
    if (threadIdx.x == 0) {
        atomicMin(&mm[0], encf(slo[0]));
        atomicMax(&mm[1], encf(shi[0]));
    }
}

// K2: voxel key per element (bit-exact replication of reference f32 math) + bucket histogram
__global__ void k_lin(const float* __restrict__ means, const u32* __restrict__ mm,
                      u32* __restrict__ lin, u32* __restrict__ cnt, int B, int N) {
    int t = blockIdx.x * blockDim.x + threadIdx.x;
    int total = B * N;
    if (t >= total) return;
    float mmin = decf(mm[0]), mmax = decf(mm[1]);
    float range = mmax - mmin;
    int vn = (int)floorf(range / 0.001f) + 1;
    if (vn > 1000) vn = 1000;
    float denom = range + 1e-6f;
    float vnf = (float)vn;
    int b = t / N;
    const float* m = means + (size_t)t * 3;
    u32 key = 0;
    #pragma unroll
    for (int k = 0; k < 3; k++) {
        float norm = (m[k] - mmin) / denom;     // IEEE div, matches reference exactly
        int v = (int)floorf(norm * vnf);
        if (v < 0) v = 0;
        if (v > vn - 1) v = vn - 1;
        key = key * (u32)vn + (u32)v;
    }
    lin[t] = key;
    atomicAdd(&cnt[b * NBINS + (key >> BBITS)], 1u);
}

// K3/K6: exclusive scan of NBINS bins per batch; one block of 1024 per batch. In-place safe.
__global__ void __launch_bounds__(1024) k_scan(const u32* __restrict__ in, u32* __restrict__ out, int nbins) {
    __shared__ u32 lds[1024];
    int b = blockIdx.x;
    u32 carry = 0;
    for (int base = 0; base < nbins; base += 1024) {
        int i = base + threadIdx.x;
        u32 v = in[b * nbins + i];
        lds[threadIdx.x] = v;
        __syncthreads();
        for (int ofs = 1; ofs < 1024; ofs <<= 1) {
            u32 tmp = (threadIdx.x >= ofs) ? lds[threadIdx.x - ofs] : 0u;
            __syncthreads();
            lds[threadIdx.x] += tmp;
            __syncthreads();
        }
        u32 incl = lds[threadIdx.x];
        u32 tot = lds[1023];
        out[b * nbins + i] = incl - v + carry;
        carry += tot;
        __syncthreads();
    }
}

// K4: scatter elements into bucket-partitioned order (off becomes end pointers)
__global__ void k_scatter(const u32* __restrict__ lin, u32* __restrict__ off,
                          u32* __restrict__ skey, u32* __restrict__ sidx, int B, int N) {
    int t = blockIdx.x * blockDim.x + threadIdx.x;
    int total = B * N;
    if (t >= total) return;
    int b = t / N, n = t - b * N;
    u32 key = lin[t];
    u32 p = atomicAdd(&off[b * NBINS + (key >> BBITS)], 1u);
    skey[(size_t)b * N + p] = key;
    sidx[(size_t)b * N + p] = (u32)n;
}

// K5: per element, distinct-rank within its bucket; bucket leader writes distinct count
__global__ void k_bucketrank(const u32* __restrict__ skey, const u32* __restrict__ sidx,
                             const u32* __restrict__ off, const u32* __restrict__ cnt,
                             u32* __restrict__ darr, u32* __restrict__ ubkt, int B, int N) {
    int t = blockIdx.x * blockDim.x + threadIdx.x;
    int total = B * N;
    if (t >= total) return;
    int b = t / N;
    u32 p = (u32)(t - b * N);
    u32 key = skey[t];
    u32 bkt = key >> BBITS;
    u32 end = off[b * NBINS + bkt];
    u32 c = cnt[b * NBINS + bkt];
    u32 start = end - c;
    const u32* kk = skey + (size_t)b * N;
    u32 d = 0;
    for (u32 q = start; q < end; q++) {
        u32 kq = kk[q];
        if (kq < key) {
            bool rep = true;
            for (u32 r = start; r < q; r++) {
                if (kk[r] == kq) { rep = false; break; }
            }
            if (rep) d++;
        }
    }
    darr[(size_t)b * N + sidx[t]] = d;
    if (p == start) {
        u32 u = 0;
        for (u32 q = start; q < end; q++) {
            u32 kq = kk[q];
            bool rep = true;
            for (u32 r = start; r < q; r++) {
                if (kk[r] == kq) { rep = false; break; }
            }
            if (rep) u++;
        }
        ubkt[b * NBINS + bkt] = u;
    }
}

// K7: final dense rank + segment max of scores (encoded atomicMax)
__global__ void k_rank_smax(const u32* __restrict__ lin, const u32* __restrict__ darr,
                            const u32* __restrict__ ubase, const float* __restrict__ scores,
                            u32* __restrict__ rankv, u32* __restrict__ smax, int B, int N) {
    int t = blockIdx.x * blockDim.x + threadIdx.x;
    int total = B * N;
    if (t >= total) return;
    int b = t / N;
    u32 key = lin[t];
    u32 r = ubase[b * NBINS + (key >> BBITS)] + darr[t];
    rankv[t] = r;
    atomicMax(&smax[(size_t)b * N + r], encf(scores[t]));
}

// K8: exp(sc - smax) + segment denominator
__global__ void k_denom(const u32* __restrict__ rankv, const float* __restrict__ scores,
                        const u32* __restrict__ smax, float* __restrict__ earr,
                        float* __restrict__ denom, int B, int N) {
    int t = blockIdx.x * blockDim.x + threadIdx.x;
    int total = B * N;
    if (t >= total) return;
    int b = t / N;
    u32 r = rankv[t];
    float m = decf(smax[(size_t)b * N + r]);
    float e = expf(scores[t] - m);
    earr[t] = e;
    atomicAdd(&denom[(size_t)b * N + r], e);
}

// K9: weighted scatter-add of all outputs
__global__ void k_out(const u32* __restrict__ rankv, const float* __restrict__ earr,
                      const float* __restrict__ denom,
                      const float* __restrict__ means, const float* __restrict__ cov,
                      const float* __restrict__ harm, const float* __restrict__ opac,
                      float* __restrict__ out, int B, int N) {
    int t = blockIdx.x * blockDim.x + threadIdx.x;
    int total = B * N;
    if (t >= total) return;
    int b = t / N;
    u32 r = rankv[t];
    float w = earr[t] / denom[(size_t)b * N + r];
    size_t src = (size_t)t;
    size_t dst = (size_t)b * N + r;
    float* om = out;                               // [B*N*3]
    float* oc = out + (size_t)B * N * 3;           // [B*N*9]
    float* oh = oc + (size_t)B * N * 9;            // [B*N*75]
    float* oo = oh + (size_t)B * N * 75;           // [B*N]
    #pragma unroll
    for (int k = 0; k < 3; k++)
        atomicAdd(&om[dst * 3 + k], means[src * 3 + k] * w);
    #pragma unroll
    for (int k = 0; k < 9; k++)
        atomicAdd(&oc[dst * 9 + k], cov[src * 9 + k] * w);
    #pragma unroll
    for (int k = 0; k < 75; k++)
        atomicAdd(&oh[dst * 75 + k], harm[src * 75 + k] * w);
    atomicAdd(&oo[dst], opac[src] * w);
}

extern "C" void kernel_launch(void* const* d_in, const int* in_sizes, int n_in,
                              void* d_out, int out_size, void* d_ws, size_t ws_size,
                              hipStream_t stream) {
    const float* scores = (const float*)d_in[0];
    const float* means  = (const float*)d_in[1];
    const float* cov    = (const float*)d_in[2];
    const float* harm   = (const float*)d_in[3];
    const float* opac   = (const float*)d_in[4];

    const int B = 4;
    const int N = in_sizes[4] / B;   // opacities [B,N]
    const int total = B * N;

    // workspace layout
    u8* w = (u8*)d_ws;
    u32* mm   = (u32*)w;                         // 2 u32 (encoded min/max)
    u32* lin  = (u32*)(w + 256);                 // B*N
    u32* cnt  = lin + (size_t)total;             // B*NBINS
    u32* off  = cnt + (size_t)B * NBINS;         // B*NBINS
    u32* ubkt = off + (size_t)B * NBINS;         // B*NBINS
    u32* skey = ubkt + (size_t)B * NBINS;        // B*N
    u32* sidx = skey + (size_t)total;            // B*N
    u32* darr = sidx + (size_t)total;            // B*N
    u32* rankv = darr + (size_t)total;           // B*N
    u32* smax  = rankv + (size_t)total;          // B*N
    float* denom = (float*)(smax + (size_t)total); // B*N
    float* earr  = denom + (size_t)total;        // B*N

    // init (ws and d_out are poisoned before every call)
    hipMemsetAsync(mm, 0xFF, 4, stream);                       // min slot = UINT_MAX
    hipMemsetAsync(mm + 1, 0x00, 4, stream);                   // max slot = 0
    hipMemsetAsync(cnt, 0, (size_t)B * NBINS * 4, stream);
    hipMemsetAsync(ubkt, 0, (size_t)B * NBINS * 4, stream);
    hipMemsetAsync(smax, 0, (size_t)total * 4, stream);        // 0 < enc(any finite float)
    hipMemsetAsync(denom, 0, (size_t)total * 4, stream);
    hipMemsetAsync(d_out, 0, (size_t)out_size * 4, stream);

    dim3 blk(256);
    dim3 grd((total + 255) / 256);

    k_minmax<<<1024, 256, 0, stream>>>(means, total * 3, mm);
    k_lin<<<grd, blk, 0, stream>>>(means, mm, lin, cnt, B, N);
    k_scan<<<B, 1024, 0, stream>>>(cnt, off, NBINS);
    k_scatter<<<grd, blk, 0, stream>>>(lin, off, skey, sidx, B, N);
    k_bucketrank<<<grd, blk, 0, stream>>>(skey, sidx, off, cnt, darr, ubkt, B, N);
    k_scan<<<B, 1024, 0, stream>>>(ubkt, ubkt, NBINS);
    k_rank_smax<<<grd, blk, 0, stream>>>(lin, darr, ubkt, scores, rankv, smax, B, N);
    k_denom<<<grd, blk, 0, stream>>>(rankv, scores, smax, earr, denom, B, N);
    k_out<<<grd, blk, 0, stream>>>(rankv, earr, denom, means, cov, harm, opac, (float*)d_out, B, N);
}

// Round 2
// 971.340 us; speedup vs baseline: 2.9714x; 2.9714x over previous
//
#include <hip/hip_runtime.h>

typedef unsigned int u32;
typedef unsigned char u8;

#define NBINS 32768
#define BBITS 15

__device__ inline u32 encf(float f) {
    u32 u = __float_as_uint(f);
    return (u & 0x80000000u) ? ~u : (u | 0x80000000u);
}
__device__ inline float decf(u32 e) {
    u32 b = (e & 0x80000000u) ? (e ^ 0x80000000u) : ~e;
    return __uint_as_float(b);
}

// K1: global min/max over all means (encoded-uint atomics; exact, order-independent)
__global__ void k_minmax(const float* __restrict__ means, int total, u32* __restrict__ mm) {
    float lo = 3.4e38f, hi = -3.4e38f;
    for (int i = blockIdx.x * blockDim.x + threadIdx.x; i < total; i += gridDim.x * blockDim.x) {
        float v = means[i];
        lo = fminf(lo, v);
        hi = fmaxf(hi, v);
    }
    __shared__ float slo[256], shi[256];
    slo[threadIdx.x] = lo; shi[threadIdx.x] = hi;
    __syncthreads();
    for (int s = 128; s > 0; s >>= 1) {
        if (threadIdx.x < s) {
            slo[threadIdx.x] = fminf(slo[threadIdx.x], slo[threadIdx.x + s]);
            shi[threadIdx.x] = fmaxf(shi[threadIdx.x], shi[threadIdx.x + s]);
        }
        __syncthreads();
    }
    if (threadIdx.x == 0) {
        atomicMin(&mm[0], encf(slo[0]));
        atomicMax(&mm[1], encf(shi[0]));
    }
}

// K2: voxel key per element (bit-exact replication of reference f32 math) + bucket histogram
__global__ void k_lin(const float* __restrict__ means, const u32* __restrict__ mm,
                      u32* __restrict__ lin, u32* __restrict__ cnt, int B, int N) {
    int t = blockIdx.x * blockDim.x + threadIdx.x;
    int total = B * N;
    if (t >= total) return;
    float mmin = decf(mm[0]), mmax = decf(mm[1]);
    float range = mmax - mmin;
    int vn = (int)floorf(range / 0.001f) + 1;
    if (vn > 1000) vn = 1000;
    float denom = range + 1e-6f;
    float vnf = (float)vn;
    int b = t / N;
    const float* m = means + (size_t)t * 3;
    u32 key = 0;
    #pragma unroll
    for (int k = 0; k < 3; k++) {
        float norm = (m[k] - mmin) / denom;     // IEEE div, matches reference exactly
        int v = (int)floorf(norm * vnf);
        if (v < 0) v = 0;
        if (v > vn - 1) v = vn - 1;
        key = key * (u32)vn + (u32)v;
    }
    lin[t] = key;
    atomicAdd(&cnt[b * NBINS + (key >> BBITS)], 1u);
}

// K3: exclusive scan of nbins values per batch; one block of 1024 per batch. In-place safe.
__global__ void __launch_bounds__(1024) k_scan(const u32* __restrict__ in, u32* __restrict__ out, int nbins) {
    __shared__ u32 lds[1024];
    int b = blockIdx.x;
    u32 carry = 0;
    for (int base = 0; base < nbins; base += 1024) {
        int i = base + threadIdx.x;
        u32 v = in[(size_t)b * nbins + i];
        lds[threadIdx.x] = v;
        __syncthreads();
        for (int ofs = 1; ofs < 1024; ofs <<= 1) {
            u32 tmp = (threadIdx.x >= ofs) ? lds[threadIdx.x - ofs] : 0u;
            __syncthreads();
            lds[threadIdx.x] += tmp;
            __syncthreads();
        }
        u32 incl = lds[threadIdx.x];
        u32 tot = lds[1023];
        out[(size_t)b * nbins + i] = incl - v + carry;
        carry += tot;
        __syncthreads();
    }
}

// K4: scatter elements into bucket-partitioned order (off becomes end pointers)
__global__ void k_scatter(const u32* __restrict__ lin, u32* __restrict__ off,
                          u32* __restrict__ skey, u32* __restrict__ sidx, int B, int N) {
    int t = blockIdx.x * blockDim.x + threadIdx.x;
    int total = B * N;
    if (t >= total) return;
    int b = t / N, n = t - b * N;
    u32 key = lin[t];
    u32 p = atomicAdd(&off[b * NBINS + (key >> BBITS)], 1u);
    skey[(size_t)b * N + p] = key;
    sidx[(size_t)b * N + p] = (u32)n;
}

// K5: per element, distinct-rank within its bucket; bucket leader writes distinct count
__global__ void k_bucketrank(const u32* __restrict__ skey, const u32* __restrict__ sidx,
                             const u32* __restrict__ off, const u32* __restrict__ cnt,
                             u32* __restrict__ darr, u32* __restrict__ ubkt, int B, int N) {
    int t = blockIdx.x * blockDim.x + threadIdx.x;
    int total = B * N;
    if (t >= total) return;
    int b = t / N;
    u32 p = (u32)(t - b * N);
    u32 key = skey[t];
    u32 bkt = key >> BBITS;
    u32 end = off[b * NBINS + bkt];
    u32 c = cnt[b * NBINS + bkt];
    u32 start = end - c;
    const u32* kk = skey + (size_t)b * N;
    u32 d = 0;
    for (u32 q = start; q < end; q++) {
        u32 kq = kk[q];
        if (kq < key) {
            bool rep = true;
            for (u32 r = start; r < q; r++) {
                if (kk[r] == kq) { rep = false; break; }
            }
            if (rep) d++;
        }
    }
    darr[(size_t)b * N + sidx[t]] = d;
    if (p == start) {
        u32 u = 0;
        for (u32 q = start; q < end; q++) {
            u32 kq = kk[q];
            bool rep = true;
            for (u32 r = start; r < q; r++) {
                if (kk[r] == kq) { rep = false; break; }
            }
            if (rep) u++;
        }
        ubkt[b * NBINS + bkt] = u;
    }
}

// K7: final dense rank + segment max of scores + per-rank member count
__global__ void k_rank_smax(const u32* __restrict__ lin, const u32* __restrict__ darr,
                            const u32* __restrict__ ubase, const float* __restrict__ scores,
                            u32* __restrict__ rankv, u32* __restrict__ smax,
                            u32* __restrict__ gcnt, int B, int N) {
    int t = blockIdx.x * blockDim.x + threadIdx.x;
    int total = B * N;
    if (t >= total) return;
    int b = t / N;
    u32 key = lin[t];
    u32 r = ubase[b * NBINS + (key >> BBITS)] + darr[t];
    rankv[t] = r;
    atomicMax(&smax[(size_t)b * N + r], encf(scores[t]));
    atomicAdd(&gcnt[(size_t)b * N + r], 1u);
}

// K8: CSR member-list build (goff becomes end pointers)
__global__ void k_build(const u32* __restrict__ rankv, u32* __restrict__ goff,
                        u32* __restrict__ glist, int B, int N) {
    int t = blockIdx.x * blockDim.x + threadIdx.x;
    int total = B * N;
    if (t >= total) return;
    int b = t / N, n = t - b * N;
    u32 r = rankv[t];
    u32 p = atomicAdd(&goff[(size_t)b * N + r], 1u);
    glist[(size_t)b * N + p] = (u32)n;
}

// K9: exp(sc - smax) + segment denominator
__global__ void k_denom(const u32* __restrict__ rankv, const float* __restrict__ scores,
                        const u32* __restrict__ smax, float* __restrict__ earr,
                        float* __restrict__ denom, int B, int N) {
    int t = blockIdx.x * blockDim.x + threadIdx.x;
    int total = B * N;
    if (t >= total) return;
    int b = t / N;
    u32 r = rankv[t];
    float m = decf(smax[(size_t)b * N + r]);
    float e = expf(scores[t] - m);
    earr[t] = e;
    atomicAdd(&denom[(size_t)b * N + r], e);
}

// K10: gather — one thread per output slot; coalesced writes, per-row contiguous reads
__global__ void k_gather(const u32* __restrict__ glist, const u32* __restrict__ goff,
                         const u32* __restrict__ gcnt,
                         const float* __restrict__ earr, const float* __restrict__ denom,
                         const float* __restrict__ means, const float* __restrict__ cov,
                         const float* __restrict__ harm, const float* __restrict__ opac,
                         float* __restrict__ out, int B, int N) {
    int t = blockIdx.x * blockDim.x + threadIdx.x;
    int total = B * N;
    if (t >= total) return;
    int b = t / N;
    size_t bn = (size_t)b * N;

    float am[3] = {0.f, 0.f, 0.f};
    float ac[9] = {0.f};
    float ah[75] = {0.f};
    float ao = 0.f;

    u32 end = goff[t];
    u32 c = gcnt[t];
    u32 start = end - c;
    float dv = (c > 0) ? denom[t] : 1.0f;

    for (u32 q = start; q < end; q++) {
        size_t e = bn + glist[bn + q];
        float w = earr[e] / dv;
        const float* pm = means + e * 3;
        const float* pc = cov + e * 9;
        const float* ph = harm + e * 75;
        #pragma unroll
        for (int k = 0; k < 3; k++) am[k] += pm[k] * w;
        #pragma unroll
        for (int k = 0; k < 9; k++) ac[k] += pc[k] * w;
        #pragma unroll
        for (int k = 0; k < 75; k++) ah[k] += ph[k] * w;
        ao += opac[e] * w;
    }

    float* om = out;                               // [B*N*3]
    float* oc = out + (size_t)B * N * 3;           // [B*N*9]
    float* oh = oc + (size_t)B * N * 9;            // [B*N*75]
    float* oo = oh + (size_t)B * N * 75;           // [B*N]
    #pragma unroll
    for (int k = 0; k < 3; k++) om[(size_t)t * 3 + k] = am[k];
    #pragma unroll
    for (int k = 0; k < 9; k++) oc[(size_t)t * 9 + k] = ac[k];
    #pragma unroll
    for (int k = 0; k < 75; k++) oh[(size_t)t * 75 + k] = ah[k];
    oo[t] = ao;
}

extern "C" void kernel_launch(void* const* d_in, const int* in_sizes, int n_in,
                              void* d_out, int out_size, void* d_ws, size_t ws_size,
                              hipStream_t stream) {
    const float* scores = (const float*)d_in[0];
    const float* means  = (const float*)d_in[1];
    const float* cov    = (const float*)d_in[2];
    const float* harm   = (const float*)d_in[3];
    const float* opac   = (const float*)d_in[4];

    const int B = 4;
    const int N = in_sizes[4] / B;   // opacities [B,N]
    const int total = B * N;

    // workspace layout
    u8* w = (u8*)d_ws;
    u32* mm   = (u32*)w;                         // 2 u32 (encoded min/max)
    u32* lin  = (u32*)(w + 256);                 // B*N
    u32* cnt  = lin + (size_t)total;             // B*NBINS
    u32* off  = cnt + (size_t)B * NBINS;         // B*NBINS
    u32* ubkt = off + (size_t)B * NBINS;         // B*NBINS
    u32* skey = ubkt + (size_t)B * NBINS;        // B*N
    u32* sidx = skey + (size_t)total;            // B*N
    u32* darr = sidx + (size_t)total;            // B*N
    u32* rankv = darr + (size_t)total;           // B*N
    u32* smax  = rankv + (size_t)total;          // B*N
    float* denom = (float*)(smax + (size_t)total); // B*N
    float* earr  = denom + (size_t)total;        // B*N
    u32* gcnt  = (u32*)(earr + (size_t)total);   // B*N
    u32* goff  = gcnt + (size_t)total;           // B*N
    u32* glist = goff + (size_t)total;           // B*N

    // init (ws and d_out are poisoned before every call)
    hipMemsetAsync(mm, 0xFF, 4, stream);                       // min slot = UINT_MAX
    hipMemsetAsync(mm + 1, 0x00, 4, stream);                   // max slot = 0
    hipMemsetAsync(cnt, 0, (size_t)B * NBINS * 4, stream);
    hipMemsetAsync(ubkt, 0, (size_t)B * NBINS * 4, stream);
    hipMemsetAsync(smax, 0, (size_t)total * 4, stream);        // 0 < enc(any finite float)
    hipMemsetAsync(denom, 0, (size_t)total * 4, stream);
    hipMemsetAsync(gcnt, 0, (size_t)total * 4, stream);

    dim3 blk(256);
    dim3 grd((total + 255) / 256);

    k_minmax<<<1024, 256, 0, stream>>>(means, total * 3, mm);
    k_lin<<<grd, blk, 0, stream>>>(means, mm, lin, cnt, B, N);
    k_scan<<<B, 1024, 0, stream>>>(cnt, off, NBINS);
    k_scatter<<<grd, blk, 0, stream>>>(lin, off, skey, sidx, B, N);
    k_bucketrank<<<grd, blk, 0, stream>>>(skey, sidx, off, cnt, darr, ubkt, B, N);
    k_scan<<<B, 1024, 0, stream>>>(ubkt, ubkt, NBINS);
    k_rank_smax<<<grd, blk, 0, stream>>>(lin, darr, ubkt, scores, rankv, smax, gcnt, B, N);
    k_scan<<<B, 1024, 0, stream>>>(gcnt, goff, N);
    k_build<<<grd, blk, 0, stream>>>(rankv, goff, glist, B, N);
    k_denom<<<grd, blk, 0, stream>>>(rankv, scores, smax, earr, denom, B, N);
    k_gather<<<grd, blk, 0, stream>>>(glist, goff, gcnt, earr, denom,
                                      means, cov, harm, opac, (float*)d_out, B, N);
}